// Round 3
// baseline (351.946 us; speedup 1.0000x reference)
//
#include <hip/hip_runtime.h>

typedef __bf16 bf16_t;
typedef bf16_t bf16x8 __attribute__((ext_vector_type(8)));
typedef bf16_t bf16x4 __attribute__((ext_vector_type(4)));
typedef float f32x4 __attribute__((ext_vector_type(4)));

#define F 512
#define NLAYERS 8
#define NLIL 8
#define TM 128

// ---- single prep pass: blocks [0,512) transpose Wbig fp32->bf16^T,
//      blocks [512,4608) convert Wlil fp32->bf16 (already B^T layout)
// (ws is re-poisoned every iteration -> prep must run every launch; the
//  magic-flag skip was tried and never fired. Keep prep minimal.)
__global__ void prep_weights(const float* __restrict__ Wbig, bf16_t* __restrict__ WbigT,
                             const float4* __restrict__ Wlil, bf16x4* __restrict__ WlilB,
                             int n4) {
  if (blockIdx.x < 512) {
    __shared__ float tile[64][65];
    const int b = blockIdx.x;
    const int l = b >> 6;
    const int tf = (b >> 3) & 7, tg = b & 7;
    const float* Wl = Wbig + (size_t)l * F * F;
    bf16_t* Ol = WbigT + (size_t)l * F * F;
    const int tx = threadIdx.x & 63;
    const int ty = threadIdx.x >> 6;  // 0..3
#pragma unroll
    for (int i = 0; i < 16; ++i) {
      int f = i * 4 + ty;
      tile[f][tx] = Wl[(size_t)(tf * 64 + f) * F + tg * 64 + tx];
    }
    __syncthreads();
#pragma unroll
    for (int i = 0; i < 16; ++i) {
      int g = i * 4 + ty;
      Ol[(size_t)(tg * 64 + g) * F + tf * 64 + tx] = (bf16_t)tile[tx][g];
    }
  } else {
    const int stride = (gridDim.x - 512) * blockDim.x;
    for (int i = (blockIdx.x - 512) * blockDim.x + threadIdx.x; i < n4; i += stride) {
      float4 v = Wlil[i];
      bf16x4 o;
      o[0] = (bf16_t)v.x; o[1] = (bf16_t)v.y; o[2] = (bf16_t)v.z; o[3] = (bf16_t)v.w;
      WlilB[i] = o;
    }
  }
}

// Y layout: fragment-major with chunk XOR swizzle.
// Logical 16B chunk of element Y[m][k]:
//   chunk = (m>>4)*1024 + (k>>5)*64 + ((k>>3)&3)*16 + (m&15), byte (k&7)*2.
// Physical chunk = logical ^ ((logical>>6)&7)  (XOR into low 3 bits).
// Compute read (mi,ks fixed): logical chunks = mi*1024 + ks*64 + lane; XOR value
// is (ks&7), constant per instruction -> reads stay ZERO-conflict (lane
// permutation of 64 contiguous chunks). The XOR spreads the banks of the
// staging / epilogue writes (which collapse to 2 banks without it).

// ---- main: persistent per-row-block 8-layer MLP chain, activations in LDS ----
// 256 blocks (1/CU): 128 big row-blocks + 8 lil models x 16 row-blocks.
// 512 threads = 8 FAT waves (2/SIMD); wave w owns cols [w*64, w*64+64):
// 4 g-tiles x 8 m-tiles -> 32 MFMA per K=32 step, acc 128 f32/lane.
// Per ks: 4 global W-frags (g-panels stay wave-exclusive: total W traffic
// unchanged vs 16 thin waves) + 8 LDS Y-frags (total LDS reads HALVE:
// 1 MB/CU/layer ~= 12K cyc < MFMA 20K cyc -> MFMA is now the busiest pipe).
// History: 16 waves 32gx128m = 192us (LDS 2MB/layer, MfmaUtil 31%);
//          16 waves 64gx64m = 305us (doubled W traffic - trap);
//          conflict-free Y alone: no gain (conflicts weren't the limiter).
template <bool PREP>
__global__ __launch_bounds__(512, 2) void fused_mlp(
    const float* __restrict__ x,
    const bf16_t* __restrict__ WbigT, const bf16_t* __restrict__ WlilT,
    const float* __restrict__ WbigF, const float* __restrict__ WlilF,
    const float* __restrict__ Bbig, const float* __restrict__ Blil,
    float* __restrict__ out) {
  __shared__ alignas(16) bf16_t Y[TM * F];  // 128 KB, fragment-major+XOR

  const int tid = threadIdx.x;
  const int lane = tid & 63;
  const int wave = tid >> 6;        // 0..7
  const int ln15 = lane & 15;
  const int q = lane >> 4;          // quad 0..3
  const int kq = q << 3;            // quad's k offset within K=32
  const int rq = q << 2;            // quad's offset along D's reg axis (g)
  const int g0 = wave * 64;         // wave's 64 output cols (exclusive panel)

  // XCD-aware block->(model,row_block): lil model m's 16 blocks pinned to XCD m.
  const int bid = blockIdx.x;
  const int xcd = bid & 7;
  const int slot = bid >> 3;
  int model, rb;
  if (slot < 16) { model = 1 + xcd; rb = slot; }
  else           { model = 0; rb = (xcd << 4) + (slot - 16); }

  const size_t grow = (model == 0) ? (size_t)rb * TM
                                   : (size_t)(16384 + (model - 1) * 2048 + rb * TM);

  // ---- stage x tile into LDS bf16 fragment-major ----
  // Global reads LINEAR (full 128B lines; the 64B-segment variant cost +36MB
  // HBM fetch). LDS write banks spread by the chunk XOR (~4-way, one-time).
  {
    const float4* xs = (const float4*)(x + grow * F);
#pragma unroll 8
    for (int i = 0; i < 32; ++i) {
      int f4 = tid + i * 512;  // 0..16383, consecutive per wave
      int row = f4 >> 7;
      int c4 = f4 & 127;
      float4 v = xs[f4];
      bf16x4 o;
      o[0] = (bf16_t)v.x; o[1] = (bf16_t)v.y; o[2] = (bf16_t)v.z; o[3] = (bf16_t)v.w;
      int chunk = ((row >> 4) * 16 + (c4 >> 3)) * 64 + ((c4 >> 1) & 3) * 16 + ln15 * 0 + (row & 15);
      chunk ^= (c4 >> 3) & 7;
      *(bf16x4*)&Y[chunk * 8 + (c4 & 1) * 4] = o;
    }
  }
  __syncthreads();

  for (int l = 0; l < NLAYERS; ++l) {
    const bf16_t* Wt = nullptr;
    const float* Wf = nullptr;
    if (PREP)
      Wt = (model == 0) ? WbigT + (size_t)l * F * F
                        : WlilT + (size_t)(l * NLIL + (model - 1)) * F * F;
    else
      Wf = (model == 0) ? WbigF + (size_t)l * F * F
                        : WlilF + (size_t)(l * NLIL + (model - 1)) * F * F;
    const float* Bp = (model == 0) ? Bbig + (size_t)l * F
                                   : Blil + (size_t)(l * NLIL + (model - 1)) * F;

    // bias is per-g (D's reg axis): one float4 covers reg 0..3; all mi share it
    f32x4 acc[4][8];
#pragma unroll
    for (int gi = 0; gi < 4; ++gi) {
      f32x4 bi = *(const f32x4*)&Bp[g0 + gi * 16 + rq];
#pragma unroll
      for (int mi = 0; mi < 8; ++mi) acc[gi][mi] = bi;
    }

#pragma unroll 2
    for (int ks = 0; ks < 16; ++ks) {
      const int kk = ks * 32 + kq;
      // A-operand: W^T rows (this wave's 64 output cols g), k-contiguous
      bf16x8 aW[4];
      if (PREP) {
#pragma unroll
        for (int gi = 0; gi < 4; ++gi)
          aW[gi] = *(const bf16x8*)&Wt[(size_t)(g0 + gi * 16 + ln15) * F + kk];
      } else if (model != 0) {
#pragma unroll
        for (int gi = 0; gi < 4; ++gi) {
          const float* p = Wf + (size_t)(g0 + gi * 16 + ln15) * F + kk;
          float4 u = *(const float4*)p;
          float4 v = *(const float4*)(p + 4);
          bf16x8 t;
          t[0] = (bf16_t)u.x; t[1] = (bf16_t)u.y; t[2] = (bf16_t)u.z; t[3] = (bf16_t)u.w;
          t[4] = (bf16_t)v.x; t[5] = (bf16_t)v.y; t[6] = (bf16_t)v.z; t[7] = (bf16_t)v.w;
          aW[gi] = t;
        }
      } else {
#pragma unroll
        for (int gi = 0; gi < 4; ++gi) {
          int col = g0 + gi * 16 + ln15;
          bf16x8 t;
#pragma unroll
          for (int j = 0; j < 8; ++j) t[j] = (bf16_t)Wf[(size_t)(kk + j) * F + col];
          aW[gi] = t;
        }
      }
      // B-operand: physical chunk = logical ^ (ks&7); zero-conflict reads
      const int ybase = (ks * 64 + (lane ^ (ks & 7))) * 8;
      bf16x8 bY[8];
#pragma unroll
      for (int mi = 0; mi < 8; ++mi)
        bY[mi] = *(const bf16x8*)&Y[mi * 8192 + ybase];
#pragma unroll
      for (int gi = 0; gi < 4; ++gi)
#pragma unroll
        for (int mi = 0; mi < 8; ++mi)
          acc[gi][mi] = __builtin_amdgcn_mfma_f32_16x16x32_bf16(aW[gi], bY[mi], acc[gi][mi], 0, 0, 0);
    }
    __syncthreads();  // all waves done READING Y before anyone overwrites it

    if (l < NLAYERS - 1) {
      // D layout (operands swapped): lane&15 = m-local, quad*4+reg = g-local.
      // Write back into fragment-major Y for the next layer (k' = g).
#pragma unroll
      for (int gi = 0; gi < 4; ++gi) {
        int g = g0 + gi * 16 + rq;
        int ks2 = g >> 5;
        int q2 = (g >> 3) & 3;
        int off = g & 7;  // 0 or 4: stays inside one 16B chunk half
#pragma unroll
        for (int mi = 0; mi < 8; ++mi) {
          bf16x4 t;
#pragma unroll
          for (int r = 0; r < 4; ++r) t[r] = (bf16_t)acc[gi][mi][r];
          int chunk = ((mi * 16 + ks2) * 64 + q2 * 16 + ln15) ^ (ks2 & 7);
          *(bf16x4*)&Y[chunk * 8 + off] = t;
        }
      }
      __syncthreads();
    } else {
      // last layer: float4 straight to output
      float* op = out + grow * F;
#pragma unroll
      for (int gi = 0; gi < 4; ++gi)
#pragma unroll
        for (int mi = 0; mi < 8; ++mi) {
          int m = mi * 16 + ln15;
          int g = g0 + gi * 16 + rq;
          *(f32x4*)&op[(size_t)m * F + g] = acc[gi][mi];
        }
    }
  }
}

extern "C" void kernel_launch(void* const* d_in, const int* in_sizes, int n_in,
                              void* d_out, int out_size, void* d_ws, size_t ws_size,
                              hipStream_t stream) {
  const float* x    = (const float*)d_in[0];
  const float* Wbig = (const float*)d_in[1];
  const float* Bbig = (const float*)d_in[2];
  const float* Wlil = (const float*)d_in[3];
  const float* Blil = (const float*)d_in[4];
  float* out = (float*)d_out;

  const size_t nWbig = (size_t)NLAYERS * F * F;         // 2,097,152
  const size_t nWlil = (size_t)NLAYERS * NLIL * F * F;  // 16,777,216
  const size_t need = (nWbig + nWlil) * sizeof(bf16_t); // ~36 MB

  if (ws_size >= need) {
    bf16_t* WbigT = (bf16_t*)d_ws;
    bf16_t* WlilB = WbigT + nWbig;
    prep_weights<<<4608, 256, 0, stream>>>(Wbig, WbigT, (const float4*)Wlil,
                                           (bf16x4*)WlilB, (int)(nWlil / 4));
    fused_mlp<true><<<256, 512, 0, stream>>>(x, WbigT, WlilB, nullptr, nullptr,
                                             Bbig, Blil, out);
  } else {
    fused_mlp<false><<<256, 512, 0, stream>>>(x, nullptr, nullptr, Wbig, Wlil,
                                              Bbig, Blil, out);
  }
}